// Round 3
// baseline (233.921 us; speedup 1.0000x reference)
//
#include <hip/hip_runtime.h>
#include <hip/hip_bf16.h>

// TDNN as GEMM, 256x256 tile, 4 quadrant-phases/K-tile with one-phase-ahead
// register pipelining (reads for phase p+1 issued during phase p's MFMA).
//   out[m,o] = relu(bias[o] + sum_kk A[m,kk]*W[kk,o])
//   A[m,kk] = x[b, t+kw, c] (contiguous 2560-elem slice), W[kk,o] = kernel[o,c,kw]

#define BATCH 64
#define SEQ   1000
#define CIN   512
#define COUT  512
#define TOUT  996
#define KTOT  2560
#define MTOT  63744
#define NKT   40            // K-tiles of 64
#define MT    249           // MTOT/256
#define NT    2             // COUT/256
#define NWG   (MT*NT)       // 498

typedef __bf16 bf16x8 __attribute__((ext_vector_type(8)));
typedef float  f32x4  __attribute__((ext_vector_type(4)));

__device__ __forceinline__ void gload_lds16(const void* g, void* l) {
  __builtin_amdgcn_global_load_lds(
      (const __attribute__((address_space(1))) void*)g,
      (__attribute__((address_space(3))) void*)l, 16, 0, 0);
}

#define BAR()    __builtin_amdgcn_s_barrier()
#define VM4()    asm volatile("s_waitcnt vmcnt(4)" ::: "memory")
#define VM0()    asm volatile("s_waitcnt vmcnt(0)" ::: "memory")
#define PRIO(x)  __builtin_amdgcn_s_setprio(x)
#define SCHED0() __builtin_amdgcn_sched_barrier(0)
#define MFMA(d, x, y) d = __builtin_amdgcn_mfma_f32_16x16x32_bf16(x, y, d, 0, 0, 0)

// ---- x fp32 -> bf16 ----
__global__ void cvt_x_kernel(const float* __restrict__ x, __bf16* __restrict__ xb, int n) {
  int i = (blockIdx.x * blockDim.x + threadIdx.x) * 8;
  if (i >= n) return;
  float4 f0 = *(const float4*)(x + i);
  float4 f1 = *(const float4*)(x + i + 4);
  bf16x8 v;
  v[0] = (__bf16)f0.x; v[1] = (__bf16)f0.y; v[2] = (__bf16)f0.z; v[3] = (__bf16)f0.w;
  v[4] = (__bf16)f1.x; v[5] = (__bf16)f1.y; v[6] = (__bf16)f1.z; v[7] = (__bf16)f1.w;
  *(bf16x8*)(xb + i) = v;
}

// ---- kernel [O][C][KW] fp32 -> Wt [O][KTOT] bf16, Wt[o][kw*512+c] ----
__global__ void cvt_w_kernel(const float* __restrict__ k, __bf16* __restrict__ wt) {
  int idx = blockIdx.x * blockDim.x + threadIdx.x;
  if (idx >= COUT * KTOT) return;
  int o  = idx / KTOT;
  int r  = idx - o * KTOT;
  int kw = r >> 9;
  int c  = r & 511;
  wt[idx] = (__bf16)k[(o * CIN + c) * 5 + kw];
}

// stage one half-tile (128 rows x 64 bf16 = 16KiB): 2 x global_load_lds(16B)/thread
#define STAGE_A(buf, h, kt) do { \
    char* d_ = (char*)&Ab[buf][h][0][0]; \
    gload_lds16(Xb + offA##h##0 + (kt)*64, d_ + dof0); \
    gload_lds16(Xb + offA##h##1 + (kt)*64, d_ + dof1); } while (0)
#define STAGE_B(buf, h, kt) do { \
    char* d_ = (char*)&Bb[buf][h][0][0]; \
    gload_lds16(Wt + offB##h##0 + (kt)*64, d_ + dof0); \
    gload_lds16(Wt + offB##h##1 + (kt)*64, d_ + dof1); } while (0)

// register-fragment reads (T2 swizzle on the read side matches source pre-swizzle)
#define RD_A(base, mi, ks) (*(const bf16x8*)((base) + ((mi)*16 + frow)*128 + ((((ks)*64 + fkb)) ^ xorv)))
#define RD_B(base, nj, ks) (*(const bf16x8*)((base) + (brow0 + (nj)*16 + frow)*128 + ((((ks)*64 + fkb)) ^ xorv)))

__global__ __launch_bounds__(512, 2)
void tdnn_gemm_kernel(const __bf16* __restrict__ Xb, const __bf16* __restrict__ Wt,
                      const float* __restrict__ bias, float* __restrict__ out) {
  // 2 K-tile buffers x 2 halves x 128 rows x 64 bf16 (A and B) = 128 KiB
  __shared__ __bf16 Ab[2][2][128][64];
  __shared__ __bf16 Bb[2][2][128][64];

  const int tid  = threadIdx.x;
  const int wave = tid >> 6;
  const int lane = tid & 63;
  const int wr = wave >> 2;          // 0..1 : 128-row band (= A half)
  const int wc = wave & 3;           // 0..3 : 64-col band

  // bijective XCD swizzle: 498 = 8*62 + 2
  int bid = blockIdx.x;
  int xcd = bid & 7, jj = bid >> 3;
  const int q = NWG >> 3, r = NWG & 7;
  int swz = (xcd < r ? xcd * (q + 1) : r * (q + 1) + (xcd - r) * q) + jj;
  const int m0 = (swz >> 1) * 256;
  const int n0 = (swz & 1) * 256;

  // ---- per-thread staging offsets (pre-swizzled global source, linear LDS dest)
  int offA00, offA01, offA10, offA11, offB00, offB01, offB10, offB11, dof0, dof1;
  {
    int o16, row, ce, m, b, tt;
#define MKOFF(l, A0, A1, B0, B1, D) \
    o16 = (l)*512 + tid; row = o16 >> 3; \
    ce  = ((((o16 & 7) << 4) ^ ((row & 7) << 4)) >> 1); \
    D   = o16 * 16; \
    m = m0 + 0*128 + row; b = m / TOUT; tt = m - b * TOUT; \
    A0 = (b * SEQ + tt) * CIN + ce; \
    m = m0 + 1*128 + row; b = m / TOUT; tt = m - b * TOUT; \
    A1 = (b * SEQ + tt) * CIN + ce; \
    B0 = (n0 + 0*128 + row) * KTOT + ce; \
    B1 = (n0 + 1*128 + row) * KTOT + ce;
    MKOFF(0, offA00, offA10, offB00, offB10, dof0)
    MKOFF(1, offA01, offA11, offB01, offB11, dof1)
#undef MKOFF
  }

  // fragment read geometry
  const int frow = lane & 15;
  const int fkb  = (lane >> 4) << 4;       // 0,16,32,48 bytes
  const int xorv = (frow & 7) << 4;        // T2 read-side XOR
  const int brow0 = (wc & 1) * 64;         // local row base within B half (wc>>1)

  f32x4 acc[8][4];
  const f32x4 z = {0.f, 0.f, 0.f, 0.f};
#pragma unroll
  for (int i = 0; i < 8; i++)
#pragma unroll
    for (int j = 0; j < 4; j++) acc[i][j] = z;

  bf16x8 a03[4][2], a47[4][2], b01[2][2], b23[2][2];

  // ---- prologue: stage tile0 (4 halves) + tile1 A-halves; drain tile0; read a03/b01(0)
  STAGE_A(0, 0, 0); STAGE_A(0, 1, 0);
  STAGE_B(0, 0, 0); STAGE_B(0, 1, 0);
  STAGE_A(1, 0, 1); STAGE_A(1, 1, 1);
  VM4();
  BAR();
  {
    const char* Ac = (const char*)&Ab[0][wr][0][0];
    const char* Bc = (const char*)&Bb[0][wc >> 1][0][0];
#pragma unroll
    for (int mi = 0; mi < 4; ++mi) { a03[mi][0] = RD_A(Ac, mi, 0); a03[mi][1] = RD_A(Ac, mi, 1); }
#pragma unroll
    for (int nj = 0; nj < 2; ++nj) { b01[nj][0] = RD_B(Bc, nj, 0); b01[nj][1] = RD_B(Bc, nj, 1); }
  }

  for (int T = 0; T < NKT; ++T) {
    const int c  = T & 1;
    const int o2 = c ^ 1;
    const char* Ac = (const char*)&Ab[c][wr][0][0];
    const char* Bc = (const char*)&Bb[c][wc >> 1][0][0];
    const char* Ao = (const char*)&Ab[o2][wr][0][0];
    const char* Bo = (const char*)&Bb[o2][wc >> 1][0][0];
    const bool s1 = (T + 1 < NKT);
    const bool s2 = (T + 2 < NKT);

    // ---- p1: stage B(T+1,h0); read a47(T) (for Q2/Q4); MFMA Q1 = a03 x b01
    if (s1) STAGE_B(o2, 0, T + 1);
#pragma unroll
    for (int mi = 0; mi < 4; ++mi) { a47[mi][0] = RD_A(Ac, mi + 4, 0); a47[mi][1] = RD_A(Ac, mi + 4, 1); }
    PRIO(1);
#pragma unroll
    for (int mi = 0; mi < 4; ++mi)
#pragma unroll
      for (int nj = 0; nj < 2; ++nj) {
        MFMA(acc[mi][nj], a03[mi][0], b01[nj][0]);
        MFMA(acc[mi][nj], a03[mi][1], b01[nj][1]);
      }
    PRIO(0);
    BAR();

    // ---- p2: stage B(T+1,h1); read b23(T) (for Q3/Q4); MFMA Q2 = a47 x b01
    if (s1) STAGE_B(o2, 1, T + 1);
#pragma unroll
    for (int nj = 0; nj < 2; ++nj) { b23[nj][0] = RD_B(Bc, nj + 2, 0); b23[nj][1] = RD_B(Bc, nj + 2, 1); }
    PRIO(1);
#pragma unroll
    for (int mi = 0; mi < 4; ++mi)
#pragma unroll
      for (int nj = 0; nj < 2; ++nj) {
        MFMA(acc[mi + 4][nj], a47[mi][0], b01[nj][0]);
        MFMA(acc[mi + 4][nj], a47[mi][1], b01[nj][1]);
      }
    PRIO(0);
    BAR();
    // all reads of buf c's A region (a03@p4(T-1), a47@p1) completed before this point

    // ---- p3: stage A(T+2,h0) into buf c; MFMA Q3 = a03 x b23
    if (s2) STAGE_A(c, 0, T + 2);
    PRIO(1);
#pragma unroll
    for (int mi = 0; mi < 4; ++mi)
#pragma unroll
      for (int nj = 0; nj < 2; ++nj) {
        MFMA(acc[mi][nj + 2], a03[mi][0], b23[nj][0]);
        MFMA(acc[mi][nj + 2], a03[mi][1], b23[nj][1]);
      }
    PRIO(0);
    BAR();

    // ---- p4: stage A(T+2,h1); counted drain of tile T+1; BAR; prefetch reads
    //      a03/b01(T+1) from the other buffer; MFMA Q4 = a47 x b23
    if (s2) STAGE_A(c, 1, T + 2);
    if (s2) { VM4(); } else { VM0(); }
    BAR();   // after this barrier, ALL waves' stages of tile T+1 have landed
    if (s1) {
#pragma unroll
      for (int mi = 0; mi < 4; ++mi) { a03[mi][0] = RD_A(Ao, mi, 0); a03[mi][1] = RD_A(Ao, mi, 1); }
#pragma unroll
      for (int nj = 0; nj < 2; ++nj) { b01[nj][0] = RD_B(Bo, nj, 0); b01[nj][1] = RD_B(Bo, nj, 1); }
    }
    SCHED0();  // keep prefetch reads issued before the MFMA cluster
    PRIO(1);
#pragma unroll
    for (int mi = 0; mi < 4; ++mi)
#pragma unroll
      for (int nj = 0; nj < 2; ++nj) {
        MFMA(acc[mi + 4][nj + 2], a47[mi][0], b23[nj][0]);
        MFMA(acc[mi + 4][nj + 2], a47[mi][1], b23[nj][1]);
      }
    PRIO(0);
    // no trailing barrier: next p1's stage targets a region whose last reads
    // completed >=2 barriers ago (liveness audited)
  }

  // ---- epilogue: bias + relu + store. C/D map: col=lane&15, row=(lane>>4)*4+reg
  const int ccol = lane & 15;
  const int crow = (lane >> 4) * 4;
  float bv[4];
#pragma unroll
  for (int nj = 0; nj < 4; ++nj)
    bv[nj] = bias[n0 + wc * 64 + nj * 16 + ccol];

#pragma unroll
  for (int mi = 0; mi < 8; ++mi) {
    const int mrow = m0 + wr * 128 + mi * 16 + crow;
#pragma unroll
    for (int nj = 0; nj < 4; ++nj) {
      const int ocol = n0 + wc * 64 + nj * 16 + ccol;
#pragma unroll
      for (int j = 0; j < 4; ++j) {
        float v = acc[mi][nj][j] + bv[nj];
        v = v > 0.f ? v : 0.f;
        out[(size_t)(mrow + j) * COUT + ocol] = v;
      }
    }
  }
}

extern "C" void kernel_launch(void* const* d_in, const int* in_sizes, int n_in,
                              void* d_out, int out_size, void* d_ws, size_t ws_size,
                              hipStream_t stream) {
  const float* x      = (const float*)d_in[0];   // [64,1000,512] fp32
  const float* kernel = (const float*)d_in[1];   // [512,512,5]   fp32
  const float* bias   = (const float*)d_in[2];   // [512]         fp32
  float* out          = (float*)d_out;           // [64,996,512]  fp32

  __bf16* xb = (__bf16*)d_ws;
  __bf16* wt = (__bf16*)((char*)d_ws + (size_t)BATCH * SEQ * CIN * 2);

  const int nx = BATCH * SEQ * CIN;              // 32,768,000
  cvt_x_kernel<<<nx / 8 / 256, 256, 0, stream>>>(x, xb, nx);
  cvt_w_kernel<<<(COUT * KTOT + 255) / 256, 256, 0, stream>>>(kernel, wt);
  tdnn_gemm_kernel<<<NWG, 512, 0, stream>>>(xb, wt, bias, out);
}

// Round 4
// 201.139 us; speedup vs baseline: 1.1630x; 1.1630x over previous
//
#include <hip/hip_runtime.h>
#include <hip/hip_bf16.h>

// TDNN as GEMM: out[m,o] = relu(bias[o] + sum_kk A[m,kk]*W[kk,o])
//   A[m,kk] = x[b, t+kw, c] (contiguous 2560-elem slice of x)
//   B (Wt2) kept OUT of LDS: fragment-native global layout, register-prefetched
//   from L2 one K-tile ahead. A: 4-buffer LDS rotation, 1 barrier + counted
//   vmcnt(12) per K-tile (T4). T2 XOR-swizzle on A. 256x256 tile, 8 waves.

#define BATCH 64
#define SEQ   1000
#define CIN   512
#define COUT  512
#define TOUT  996
#define KTOT  2560
#define MTOT  63744
#define NKT   40            // K-tiles of 64
#define MT    249           // MTOT/256
#define NT    2             // COUT/256
#define NWG   (MT*NT)       // 498

typedef __bf16 bf16x8 __attribute__((ext_vector_type(8)));
typedef float  f32x4  __attribute__((ext_vector_type(4)));

__device__ __forceinline__ void gload_lds16(const void* g, void* l) {
  __builtin_amdgcn_global_load_lds(
      (const __attribute__((address_space(1))) void*)g,
      (__attribute__((address_space(3))) void*)l, 16, 0, 0);
}

#define BAR()    __builtin_amdgcn_s_barrier()
#define VM12()   asm volatile("s_waitcnt vmcnt(12)" ::: "memory")
#define VM8()    asm volatile("s_waitcnt vmcnt(8)"  ::: "memory")
#define VM4()    asm volatile("s_waitcnt vmcnt(4)"  ::: "memory")
#define PRIO(x)  __builtin_amdgcn_s_setprio(x)
#define SCHED0() __builtin_amdgcn_sched_barrier(0)
#define MFMA(d, x, y) d = __builtin_amdgcn_mfma_f32_16x16x32_bf16(x, y, d, 0, 0, 0)

// ---- x fp32 -> bf16 ----
__global__ void cvt_x_kernel(const float* __restrict__ x, __bf16* __restrict__ xb, int n) {
  int i = (blockIdx.x * blockDim.x + threadIdx.x) * 8;
  if (i >= n) return;
  float4 f0 = *(const float4*)(x + i);
  float4 f1 = *(const float4*)(x + i + 4);
  bf16x8 v;
  v[0] = (__bf16)f0.x; v[1] = (__bf16)f0.y; v[2] = (__bf16)f0.z; v[3] = (__bf16)f0.w;
  v[4] = (__bf16)f1.x; v[5] = (__bf16)f1.y; v[6] = (__bf16)f1.z; v[7] = (__bf16)f1.w;
  *(bf16x8*)(xb + i) = v;
}

// ---- kernel [O][C][KW] fp32 -> Wt2 fragment-native bf16 ----
// layout: elem idx = ((ks*32 + ob)*64 + l)*8 + j
//   col o = ob*16 + (l&15); k = ks*32 + ((l>>4)&3)*8 + j; c = k&511; kw = k>>9
__global__ void cvt_w_kernel(const float* __restrict__ k, __bf16* __restrict__ wt) {
  int idx = blockIdx.x * blockDim.x + threadIdx.x;   // 1,310,720
  if (idx >= 80 * 32 * 512) return;
  int j  = idx & 7;
  int l  = (idx >> 3) & 63;
  int t1 = idx >> 9;
  int ob = t1 & 31;
  int ks = t1 >> 5;
  int o  = ob * 16 + (l & 15);
  int kk = ks * 32 + ((l >> 4) & 3) * 8 + j;
  int c  = kk & 511, kw = kk >> 9;
  wt[idx] = (__bf16)k[(o * CIN + c) * 5 + kw];
}

// stage one full A K-tile (256 rows x 64 bf16 = 32KiB): 4 x gload_lds16/thread
#define STAGE(buf, kt) do { \
    char* d_ = (char*)Ab + ((buf) << 15); \
    gload_lds16(Xb + offA0 + (kt) * 64, d_ + dof0); \
    gload_lds16(Xb + offA1 + (kt) * 64, d_ + dof1); \
    gload_lds16(Xb + offA2 + (kt) * 64, d_ + dof2); \
    gload_lds16(Xb + offA3 + (kt) * 64, d_ + dof3); } while (0)

// load next-tile B fragments from global (L2-resident), 8 x dwordx4
#define LOADB(bn, Tn) do { \
    const char* p_ = Wglob + (size_t)(Tn) * 65536; \
    bn[0][0] = *(const bf16x8*)(p_ +     0); bn[0][1] = *(const bf16x8*)(p_ + 32768); \
    bn[1][0] = *(const bf16x8*)(p_ +  1024); bn[1][1] = *(const bf16x8*)(p_ + 33792); \
    bn[2][0] = *(const bf16x8*)(p_ +  2048); bn[2][1] = *(const bf16x8*)(p_ + 34816); \
    bn[3][0] = *(const bf16x8*)(p_ +  3072); bn[3][1] = *(const bf16x8*)(p_ + 35840); } while (0)

// one K-tile: prefetch B(T+1)->regs, stage A(T+2)->LDS, 16 ds_read + 64 MFMA,
// counted vmcnt + single barrier.
#define TILE(T, bc, bn) do { \
    const bool s1_ = (T) + 1 < NKT, s2_ = (T) + 2 < NKT; \
    if (s1_) LOADB(bn, (T) + 1); \
    if (s2_) STAGE(((T) + 2) & 3, (T) + 2); \
    const char* Ac_ = Aw + (((T) & 3) << 15); \
    bf16x8 a_[4][2]; \
    _Pragma("unroll") \
    for (int mi = 0; mi < 4; ++mi) { \
      a_[mi][0] = *(const bf16x8*)(Ac_ + mi * 2048 + off0); \
      a_[mi][1] = *(const bf16x8*)(Ac_ + mi * 2048 + off1); \
    } \
    PRIO(1); \
    _Pragma("unroll") \
    for (int mi = 0; mi < 4; ++mi) \
      _Pragma("unroll") \
      for (int nj = 0; nj < 4; ++nj) { \
        MFMA(acc[mi][nj], a_[mi][0], bc[nj][0]); \
        MFMA(acc[mi][nj], a_[mi][1], bc[nj][1]); \
      } \
    PRIO(0); \
    _Pragma("unroll") \
    for (int mi = 0; mi < 4; ++mi) { \
      a_[mi][0] = *(const bf16x8*)(Ac_ + (mi + 4) * 2048 + off0); \
      a_[mi][1] = *(const bf16x8*)(Ac_ + (mi + 4) * 2048 + off1); \
    } \
    PRIO(1); \
    _Pragma("unroll") \
    for (int mi = 0; mi < 4; ++mi) \
      _Pragma("unroll") \
      for (int nj = 0; nj < 4; ++nj) { \
        MFMA(acc[mi + 4][nj], a_[mi][0], bc[nj][0]); \
        MFMA(acc[mi + 4][nj], a_[mi][1], bc[nj][1]); \
      } \
    PRIO(0); \
    SCHED0(); \
    if (s2_) { VM12(); } else if (s1_) { VM8(); } \
    if (s1_) BAR(); \
  } while (0)

__global__ __launch_bounds__(512, 2)
void tdnn_gemm_kernel(const __bf16* __restrict__ Xb, const __bf16* __restrict__ Wt2,
                      const float* __restrict__ bias, float* __restrict__ out) {
  // A only: 4 rotating K-tile buffers x 256 rows x 64 bf16 = 128 KiB
  __shared__ __bf16 Ab[4][256][64];

  const int tid  = threadIdx.x;
  const int wave = tid >> 6;
  const int lane = tid & 63;
  const int wr = wave >> 2;          // 0..1 : 128-row band
  const int wc = wave & 3;           // 0..3 : 64-col band

  // bijective XCD swizzle: 498 = 8*62 + 2
  int bid = blockIdx.x;
  int xcd = bid & 7, jj = bid >> 3;
  const int q = NWG >> 3, r = NWG & 7;
  int swz = (xcd < r ? xcd * (q + 1) : r * (q + 1) + (xcd - r) * q) + jj;
  const int m0 = (swz >> 1) * 256;
  const int n0 = (swz & 1) * 256;

  // ---- A staging offsets (pre-swizzled global source, linear LDS dest)
  int offA0, offA1, offA2, offA3, dof0, dof1, dof2, dof3;
  {
    int o16, row, ce, m, b, tt;
#define MKOFF(l, A, D) \
    o16 = (l) * 512 + tid; row = o16 >> 3; \
    ce  = ((((o16 & 7) << 4) ^ ((row & 7) << 4)) >> 1); \
    D   = o16 * 16; \
    m = m0 + row; b = m / TOUT; tt = m - b * TOUT; \
    A = (b * SEQ + tt) * CIN + ce;
    MKOFF(0, offA0, dof0)
    MKOFF(1, offA1, dof1)
    MKOFF(2, offA2, dof2)
    MKOFF(3, offA3, dof3)
#undef MKOFF
  }

  // ---- fragment read geometry (A from LDS, T2 read-side XOR)
  const int frow = lane & 15;
  const int fkb  = (lane >> 4) << 4;        // 0,16,32,48 bytes
  const int xorv = (frow & 7) << 4;
  const int off0 = fkb ^ xorv;              // k-slice 0
  const int off1 = (64 + fkb) ^ xorv;       // k-slice 1
  const char* Aw = (const char*)Ab + (wr * 128 + frow) * 128;

  // ---- B fragment-native global base for this wave
  const int obW = (n0 >> 4) + wc * 4;
  const char* Wglob = (const char*)Wt2 + obW * 1024 + lane * 16;

  f32x4 acc[8][4];
  const f32x4 z = {0.f, 0.f, 0.f, 0.f};
#pragma unroll
  for (int i = 0; i < 8; i++)
#pragma unroll
    for (int j = 0; j < 4; j++) acc[i][j] = z;

  bf16x8 bA[4][2], bB[4][2];

  // ---- prologue: B(0)->bA, stage A(0)->buf0, A(1)->buf1; drain through A(0)
  LOADB(bA, 0);
  STAGE(0, 0);
  STAGE(1, 1);
  VM4();       // in-order: drains B(0)x8 + A(0)x4, leaves A(1)x4 in flight
  BAR();

  for (int T = 0; T < NKT; T += 2) {
    TILE(T,     bA, bB);
    TILE(T + 1, bB, bA);
  }

  // ---- epilogue: bias + relu + store. C/D map: col=lane&15, row=(lane>>4)*4+reg
  const int ccol = lane & 15;
  const int crow = (lane >> 4) * 4;
  float bv[4];
#pragma unroll
  for (int nj = 0; nj < 4; ++nj)
    bv[nj] = bias[n0 + wc * 64 + nj * 16 + ccol];

#pragma unroll
  for (int mi = 0; mi < 8; ++mi) {
    const int mrow = m0 + wr * 128 + mi * 16 + crow;
#pragma unroll
    for (int nj = 0; nj < 4; ++nj) {
      const int ocol = n0 + wc * 64 + nj * 16 + ccol;
#pragma unroll
      for (int j = 0; j < 4; ++j) {
        float v = acc[mi][nj][j] + bv[nj];
        v = v > 0.f ? v : 0.f;
        out[(size_t)(mrow + j) * COUT + ocol] = v;
      }
    }
  }
}

extern "C" void kernel_launch(void* const* d_in, const int* in_sizes, int n_in,
                              void* d_out, int out_size, void* d_ws, size_t ws_size,
                              hipStream_t stream) {
  const float* x      = (const float*)d_in[0];   // [64,1000,512] fp32
  const float* kernel = (const float*)d_in[1];   // [512,512,5]   fp32
  const float* bias   = (const float*)d_in[2];   // [512]         fp32
  float* out          = (float*)d_out;           // [64,996,512]  fp32

  __bf16* xb  = (__bf16*)d_ws;
  __bf16* wt2 = (__bf16*)((char*)d_ws + (size_t)BATCH * SEQ * CIN * 2);

  const int nx = BATCH * SEQ * CIN;              // 32,768,000
  cvt_x_kernel<<<nx / 8 / 256, 256, 0, stream>>>(x, xb, nx);
  cvt_w_kernel<<<(80 * 32 * 512 + 255) / 256, 256, 0, stream>>>(kernel, wt2);
  tdnn_gemm_kernel<<<NWG, 512, 0, stream>>>(xb, wt2, bias, out);
}